// Round 4
// baseline (200.448 us; speedup 1.0000x reference)
//
#include <hip/hip_runtime.h>

#define D_ 160
#define H_ 192
#define W_ 160
#define HW_ (H_*W_)
#define V_ (D_*H_*W_)
#define NTOT (2*V_)

#define TW 32
#define TH 24            // R12: 24 output rows/tile (was 16)
#define DC 20
#define NCHUNK (D_/DC)    // 8
#define RH 32             // TH + 8 halo
#define TWP 33            // ws stride pad (33%8==1 -> uniform quad-banks)
#define NBLOCKS (5*8*NCHUNK*2)   // 640

// 16B zero page for boundary/out-of-range DMA sources (L2-resident; keeps
// per-wave global_load_lds issue count uniform so counted vmcnt is sound).
__device__ __align__(64) float zpad_g[4] = {0.f, 0.f, 0.f, 0.f};

// 16B global->LDS DMA. LDS dest = wave-uniform base + lane*16 (m97/m104).
#define GLD16(gp, lp) \
  __builtin_amdgcn_global_load_lds( \
      (const __attribute__((address_space(1))) unsigned int*)(const void*)(gp), \
      (__attribute__((address_space(3))) unsigned int*)(void*)(lp), 16, 0, 0)

// RTNE f32x2 -> packed bf16x2 and back (validated R5/R6/R8: absmax 0.0).
__device__ inline unsigned pack_bf2(float a, float b) {
  unsigned ua = __float_as_uint(a), ub = __float_as_uint(b);
  ua += 0x7fffu + ((ua >> 16) & 1u);
  ub += 0x7fffu + ((ub >> 16) & 1u);
  return (ua & 0xffff0000u) | (ub >> 16);
}
__device__ inline float2 unpack_bf2(unsigned u) {
  return make_float2(__uint_as_float(u & 0xffff0000u),
                     __uint_as_float(u << 16));
}

// ---------------------------------------------------------------------------
// Fused separable 9x9x9 box filter + NCC.
// R9:  counted vmcnt + raw barriers -> 111 -> 87 us.
// R10: FAILED: launch_bounds(256,4) reg-guarantee spilled (WRITE_SIZE 97MB).
// R11: NEUTRAL: 4 blocks/CU + depth-2 prefetch, dur unchanged 86 us.
//      Diagnosis: LDS-THROUGHPUT-BOUND. Per block-step LDS pipe demand
//      ~1550 cyc (C 712 + B 432 + conflicts 403); wall = max-blocks-per-CU(4)
//      x 30 steps x 1550 = 186K cyc = 77us ~= measured. Residency/prefetch
//      don't matter; only (LDS work per CU) does.
// R12: cut LDS work per output + balance:
//  (a) TH 16->24 (grid 640): C does 3 rows/thread -> 11 element-reads per
//      3 outputs (was 10 per 2): -33% on the dominant C term. B halo ratio
//      32/24 vs 24/16. B code unchanged (32 rows x 8 runs = 256 thr exactly).
//  (b) 640 blocks at 3/CU (LDS 52.9KB) = single round, max-CU load 3 blocks.
//      Per-CU LDS ~ 3x30x1800 = 162K cyc ~ 67us predicted.
// Staging: 640 quads/slice, 3 issues/thread; phantom issues (waves 2-3 of
// issue 2) DMA zero-page -> 1KB dump so per-wave vmcnt stays uniform (3/step,
// depth 2 -> vmcnt(6), tail 3/0).
// Pipeline (u = t mod 9; t%3 == u%3 since 9%3==0):
//   stage(t): slice t -> sIJ[t%3]                 t in [0,28)
//   C(t):     ws (slice t-3) H-sums + D-ring      t in [3,31), emit t>=11
//   mid-bar:  vmcnt(6|3|0) + s_barrier            t in [2,30)
//   B(t):     sIJ[(t-2)%3] -> W-sums -> ws        t in [2,30)
//   end-bar:  lgkmcnt(0) + s_barrier              t in [2,30)
// ---------------------------------------------------------------------------
__global__ __launch_bounds__(256, 3) void ncc_fused(const float* __restrict__ I,
                                                    const float* __restrict__ J,
                                                    float* __restrict__ bsum) {
  __shared__ float4 sIJ[3][640];       // 30720 B [buf][ I 0..319 | J 320..639 ]
  __shared__ float4 dump[64];          //  1024 B phantom-DMA dest
  __shared__ float4 ws4[RH][TWP];      // 16896 B W-sums f0-3
  __shared__ float  ws1[RH][TWP];      //  4224 B W-sums f4
                                       // total 52864 B -> 3 blocks/CU

  const int tid = threadIdx.x;
  const int w0 = blockIdx.x * TW;               // 5
  const int h0 = blockIdx.y * TH;               // 8
  const int c0 = (blockIdx.z % NCHUNK) * DC;    // 8 chunks
  const int batch = blockIdx.z / NCHUNK;        // 2

  const float* Ib = I + (size_t)batch * V_;
  const float* Jb = J + (size_t)batch * V_;
  const float* zp = zpad_g;

  // Staging: 640 quads/slice. chunk g: arr=g/320, rem=g%320, row r=rem/10
  // (h=h0-4+r, r in 0..31), quad q=rem%10 (col=w0-4+4q). 3 chunks/thread:
  // g = tid, tid+256, tid+512 (512.. only tid<128 real; waves 2-3 -> dump).
  const int g0 = tid, g1 = tid + 256, g2 = tid + 512;
  const int a0 = g0 / 320, rem0 = g0 % 320;
  const int r0 = rem0 / 10, q0 = rem0 % 10;
  const int h0g = h0 - 4 + r0, c0g = w0 - 4 + 4 * q0;
  const bool ok0 = ((unsigned)h0g < (unsigned)H_) && ((unsigned)c0g < (unsigned)W_);
  const float* gb0 = (a0 ? Jb : Ib) + (ok0 ? ((size_t)h0g * W_ + c0g) : 0);

  const int a1 = g1 / 320, rem1 = g1 % 320;
  const int r1 = rem1 / 10, q1 = rem1 % 10;
  const int h1g = h0 - 4 + r1, c1g = w0 - 4 + 4 * q1;
  const bool ok1 = ((unsigned)h1g < (unsigned)H_) && ((unsigned)c1g < (unsigned)W_);
  const float* gb1 = (a1 ? Jb : Ib) + (ok1 ? ((size_t)h1g * W_ + c1g) : 0);

  const int a2 = (g2 / 320) & 1, rem2 = g2 % 320;
  const int r2 = rem2 / 10, q2 = rem2 % 10;
  const int h2g = h0 - 4 + r2, c2g = w0 - 4 + 4 * q2;
  const bool ok2 = (g2 < 640) && ((unsigned)h2g < (unsigned)H_) && ((unsigned)c2g < (unsigned)W_);
  const float* gb2 = (a2 ? Jb : Ib) + (ok2 ? ((size_t)h2g * W_ + c2g) : 0);

  // Wave-uniform LDS byte bases for the three DMA issues.
  const int wv  = tid >> 6;
  const int wb0 = wv * 1024;             // chunks [      wv*64, +64)
  const int wb1 = 4096 + wv * 1024;      // chunks [256 + wv*64, +64)
  const int wb2 = 8192 + wv * 1024;      // chunks [512 + wv*64, +64) (wv<2)

  // B mapping (all 256): 32 rows x 8 runs of 4
  const int br = tid >> 3;
  const int brun = tid & 7;
  const int bc = brun * 4;

  // C mapping: col tx, output rows hb, hb+1, hb+2
  const int tx = tid & 31;
  const int hb = (tid >> 5) * 3;

  unsigned ringA[5][9];   // points (hb, hb+1) packed bf16x2
  unsigned ringB[5][9];   // point  (hb+2) in high half
  float sum0[5], sum1[5], sum2[5];
#pragma unroll
  for (int f = 0; f < 5; ++f) {
    sum0[f] = 0.f; sum1[f] = 0.f; sum2[f] = 0.f;
#pragma unroll
    for (int k = 0; k < 9; ++k) { ringA[f][k] = 0u; ringB[f][k] = 0u; }
  }

  float local = 0.f;

#pragma unroll 1
  for (int tb = 0; tb < 36; tb += 9) {
#pragma unroll
    for (int u = 0; u < 9; ++u) {
      const int t = tb + u;          // 0..35; phases self-guard (31..35 idle)

      // ---- stage: slice s = c0-4+t -> sIJ[t%3]; EVERY wave issues 3 DMAs ----
      if (t < DC + 8) {
        const int s = c0 - 4 + t;
        const bool sin = (unsigned)s < (unsigned)D_;
        const size_t so = sin ? (size_t)s * HW_ : 0;
        char* lbase = (char*)&sIJ[u % 3][0];   // t%3 == u%3 (tb multiple of 9)
        const float* A0 = (sin && ok0) ? (gb0 + so) : zp;
        GLD16(A0, lbase + wb0);
        const float* A1 = (sin && ok1) ? (gb1 + so) : zp;
        GLD16(A1, lbase + wb1);
        const float* A2 = (sin && ok2) ? (gb2 + so) : zp;
        char* d2 = (wv < 2) ? (lbase + wb2) : (char*)&dump[0];
        GLD16(A2, d2);
      }

      // ---- C: H-dir 9-sums of ws (= slice t-3) + bf16 D-ring (slot u) ----
      if (t >= 3 && t < DC + 11) {
        float v0 = 0.f, v1 = 0.f, v2 = 0.f, v3 = 0.f, v4 = 0.f;
        float4 kA4, kB4; float kA1, kB1;
#pragma unroll
        for (int k = 0; k < 9; ++k) {
          const float4 a4 = ws4[hb + k][tx];
          const float  a1f = ws1[hb + k][tx];
          if (k == 0) { kA4 = a4; kA1 = a1f; }
          if (k == 1) { kB4 = a4; kB1 = a1f; }
          v0 += a4.x; v1 += a4.y; v2 += a4.z; v3 += a4.w; v4 += a1f;
        }
        const float4 tA4 = ws4[hb + 9][tx];
        const float  tA1 = ws1[hb + 9][tx];
        const float4 tB4 = ws4[hb + 10][tx];
        const float  tB1 = ws1[hb + 10][tx];
        float hv0[5], hv1[5], hv2[5];
        hv0[0] = v0; hv0[1] = v1; hv0[2] = v2; hv0[3] = v3; hv0[4] = v4;
        hv1[0] = v0 + tA4.x - kA4.x;
        hv1[1] = v1 + tA4.y - kA4.y;
        hv1[2] = v2 + tA4.z - kA4.z;
        hv1[3] = v3 + tA4.w - kA4.w;
        hv1[4] = v4 + tA1   - kA1;
        hv2[0] = hv1[0] + tB4.x - kB4.x;
        hv2[1] = hv1[1] + tB4.y - kB4.y;
        hv2[2] = hv1[2] + tB4.z - kB4.z;
        hv2[3] = hv1[3] + tB4.w - kB4.w;
        hv2[4] = hv1[4] + tB1   - kB1;

#pragma unroll
        for (int f = 0; f < 5; ++f) {
          const float2 oa = unpack_bf2(ringA[f][u]);
          sum0[f] += hv0[f] - oa.x;
          sum1[f] += hv1[f] - oa.y;
          ringA[f][u] = pack_bf2(hv0[f], hv1[f]);
          const float2 ob = unpack_bf2(ringB[f][u]);
          sum2[f] += hv2[f] - ob.x;
          ringB[f][u] = pack_bf2(hv2[f], 0.f);
        }

        if (t >= 11) {
          const float inv = 1.f / 729.f;
          const float cx0 = sum0[4] - sum0[0] * sum0[1] * inv;
          const float iv0 = sum0[2] - sum0[0] * sum0[0] * inv;
          const float jv0 = sum0[3] - sum0[1] * sum0[1] * inv;
          local += cx0 * cx0 * __builtin_amdgcn_rcpf(iv0 * jv0 + 1e-5f);
          const float cx1 = sum1[4] - sum1[0] * sum1[1] * inv;
          const float iv1 = sum1[2] - sum1[0] * sum1[0] * inv;
          const float jv1 = sum1[3] - sum1[1] * sum1[1] * inv;
          local += cx1 * cx1 * __builtin_amdgcn_rcpf(iv1 * jv1 + 1e-5f);
          const float cx2 = sum2[4] - sum2[0] * sum2[1] * inv;
          const float iv2 = sum2[2] - sum2[0] * sum2[0] * inv;
          const float jv2 = sum2[3] - sum2[1] * sum2[1] * inv;
          local += cx2 * cx2 * __builtin_amdgcn_rcpf(iv2 * jv2 + 1e-5f);
        }
      }

      // ---- mid barrier: drain slice t-2 (stage(t), stage(t-1) in flight).
      //      Also covers the ws WAR (C reads above, B writes below).
      if (t >= 2 && t < DC + 10) {
        if (t < DC + 8) {
          asm volatile("s_waitcnt vmcnt(6)" ::: "memory");
        } else if (t == DC + 8) {
          asm volatile("s_waitcnt vmcnt(3)" ::: "memory");
        } else {
          asm volatile("s_waitcnt vmcnt(0)" ::: "memory");
        }
        __builtin_amdgcn_s_barrier();
      }

      // ---- B: W-dir 9-sums of slice t-2 from sIJ[(t-2)%3] -> ws ----
      if (t >= 2 && t < DC + 10) {
        const float4* SI = &sIJ[(u + 1) % 3][br * 10 + brun];  // (t-2)%3
        const float4* SJ = SI + 320;
        const float4 A0 = SI[0], A1 = SI[1], A2 = SI[2];
        const float4 B0 = SJ[0], B1 = SJ[1], B2 = SJ[2];
        const float ai[12] = {A0.x,A0.y,A0.z,A0.w, A1.x,A1.y,A1.z,A1.w,
                              A2.x,A2.y,A2.z,A2.w};
        const float aj[12] = {B0.x,B0.y,B0.z,B0.w, B1.x,B1.y,B1.z,B1.w,
                              B2.x,B2.y,B2.z,B2.w};
        float4* W4 = ws4[br];
        float*  W1 = ws1[br];
        float s0 = 0.f, s1 = 0.f, s2 = 0.f, s3 = 0.f, s4 = 0.f;
#pragma unroll
        for (int k = 0; k < 9; ++k) {
          const float a = ai[k], b = aj[k];
          s0 += a; s1 += b; s2 += a * a; s3 += b * b; s4 += a * b;
        }
        W4[bc] = make_float4(s0, s1, s2, s3);
        W1[bc] = s4;
#pragma unroll
        for (int m = 1; m < 4; ++m) {
          const float ea = ai[8 + m], eb = aj[8 + m];
          const float la = ai[m - 1], lb = aj[m - 1];
          s0 += ea - la;
          s1 += eb - lb;
          s2 += ea * ea - la * la;
          s3 += eb * eb - lb * lb;
          s4 += ea * eb - la * lb;
          W4[bc + m] = make_float4(s0, s1, s2, s3);
          W1[bc + m] = s4;
        }
      }

      // ---- end barrier: ws RAW to C(t+1); sIJ[(t+1)%3] readers (B(t)) done
      //      before stage(t+1) overwrites it.
      if (t >= 2 && t < DC + 10) {
        asm volatile("s_waitcnt lgkmcnt(0)" ::: "memory");
        __builtin_amdgcn_s_barrier();
      }
    }
  }

  // ---- block reduction (reuse ws4 space) -> per-block partial ----
  __syncthreads();   // C(30)'s ws reads consumed before the space is reused
  float* red = (float*)&ws4[0][0];
  red[tid] = local;
  __syncthreads();
  for (int s2 = 128; s2 > 0; s2 >>= 1) {
    if (tid < s2) red[tid] += red[tid + s2];
    __syncthreads();
  }
  if (tid == 0) {
    const int bid = (blockIdx.z * 8 + blockIdx.y) * 5 + blockIdx.x;
    bsum[bid] = red[0];
  }
}

__global__ __launch_bounds__(256) void finalize_k(const float* __restrict__ bsum,
                                                  float* __restrict__ out) {
  __shared__ double red[256];
  double d = 0.0;
  for (int i = threadIdx.x; i < NBLOCKS; i += 256) d += (double)bsum[i];
  red[threadIdx.x] = d;
  __syncthreads();
  for (int s = 128; s > 0; s >>= 1) {
    if (threadIdx.x < s) red[threadIdx.x] += red[threadIdx.x + s];
    __syncthreads();
  }
  if (threadIdx.x == 0) out[0] = (float)(-red[0] / (double)NTOT);
}

extern "C" void kernel_launch(void* const* d_in, const int* in_sizes, int n_in,
                              void* d_out, int out_size, void* d_ws, size_t ws_size,
                              hipStream_t stream) {
  const float* I = (const float*)d_in[0];   // y_true
  const float* J = (const float*)d_in[1];   // y_pred
  float* out = (float*)d_out;
  float* bsum = (float*)d_ws;               // 640 floats

  dim3 grid(W_ / TW, H_ / TH, NCHUNK * 2);  // 5 x 8 x 16 = 640 blocks
  ncc_fused<<<grid, 256, 0, stream>>>(I, J, bsum);
  finalize_k<<<1, 256, 0, stream>>>(bsum, out);
}

// Round 5
// 172.214 us; speedup vs baseline: 1.1639x; 1.1639x over previous
//
#include <hip/hip_runtime.h>

#define D_ 160
#define H_ 192
#define W_ 160
#define HW_ (H_*W_)
#define V_ (D_*H_*W_)
#define NTOT (2*V_)

#define TW 32
#define TH 16
#define DC 20
#define NCHUNK (D_/DC)    // 8
#define RH 24             // TH + 8 halo
#define TWP 33            // ws stride pad: row stride 132 dwords -> 4(row+tx)%32 starts, 2-way free
#define NBLOCKS (5*12*NCHUNK*2)   // 960

// 16B zero page for boundary/out-of-range DMA sources (L2-resident; keeps
// per-wave global_load_lds issue count uniform so counted vmcnt is sound).
__device__ __align__(64) float zpad_g[4] = {0.f, 0.f, 0.f, 0.f};

// 16B global->LDS DMA. LDS dest = wave-uniform base + lane*16 (m97/m104).
#define GLD16(gp, lp) \
  __builtin_amdgcn_global_load_lds( \
      (const __attribute__((address_space(1))) unsigned int*)(const void*)(gp), \
      (__attribute__((address_space(3))) unsigned int*)(void*)(lp), 16, 0, 0)

// RTNE f32x2 -> packed bf16x2 and back (validated R5/R6/R8: absmax 0.0).
__device__ inline unsigned pack_bf2(float a, float b) {
  unsigned ua = __float_as_uint(a), ub = __float_as_uint(b);
  ua += 0x7fffu + ((ua >> 16) & 1u);
  ub += 0x7fffu + ((ub >> 16) & 1u);
  return (ua & 0xffff0000u) | (ub >> 16);
}
__device__ inline float2 unpack_bf2(unsigned u) {
  return make_float2(__uint_as_float(u & 0xffff0000u),
                     __uint_as_float(u << 16));
}

// ---------------------------------------------------------------------------
// Fused separable 9x9x9 box filter + NCC.
// R9:  counted vmcnt + raw barriers -> 111 -> 87 us.
// R10: FAILED: launch_bounds(256,4) reg-guarantee spilled (WRITE_SIZE 97MB).
// R11: NEUTRAL: 4/CU + depth-2 prefetch, 86 us. Kernel is LDS-pipe-limited.
// R12: FAILED: TH=24 ring state spilled to scratch (WRITE_SIZE 134MB) even
//      at VGPR_Count=84 -- true demand > 170 budget, compiler demoted rings.
// R13: keep R11 skeleton (TH=16, regs ~72), cut LDS-pipe work per step:
//  (a) ws packed: float4{ x=bf16(s0,s1), y=bf16(s2,s3), z=f32 s4 }.
//      C: 10 b128 + 10 b32 -> 10 b128 per thread (178->120 cyc/wave).
//      B writes: 4 b128 + 4 b32 -> 4 b128. s4 (cross term, worst
//      cancellation) stays f32; s0..s3 bf16 noise ~3e-4 rel on cc, final
//      scalar err ~1e-7 (same noise class as the validated bf16 D-ring).
//  (b) B-write bank fix: old bc=4*brun gave start banks {0,16} = 4-way
//      conflict (the only real >=4-way in the kernel). New mapping:
//      wave w handles rows 8w+(tid&7), run=(tid>>3)&7 -> write starts
//      4*row+16*run: 16 distinct per quarter-wave = conflict-free.
// LDS: sIJ 23040 + ws4 12672 = 35712 B.
// Pipeline unchanged from R11 (u = t mod 9; t%3 == u%3):
//   stage(t): slice t -> sIJ[t%3]                 t in [0,28)
//   C(t):     ws (slice t-3) H-sums + D-ring      t in [3,31), emit t>=11
//   mid-bar:  vmcnt(4|2|0) + s_barrier            t in [2,30)
//   B(t):     sIJ[(t-2)%3] -> W-sums -> ws        t in [2,30)
//   end-bar:  lgkmcnt(0) + s_barrier              t in [2,30)
// ---------------------------------------------------------------------------
__global__ __launch_bounds__(256, 3) void ncc_fused(const float* __restrict__ I,
                                                    const float* __restrict__ J,
                                                    float* __restrict__ bsum) {
  __shared__ float4 sIJ[3][480];       // 23040 B [buf][ I 0..239 | J 240..479 ]
  __shared__ float4 ws4[RH][TWP];      // 12672 B packed W-sums
                                       // total 35712 B

  const int tid = threadIdx.x;
  const int w0 = blockIdx.x * TW;               // 5
  const int h0 = blockIdx.y * TH;               // 12
  const int c0 = (blockIdx.z % NCHUNK) * DC;    // 8 chunks
  const int batch = blockIdx.z / NCHUNK;        // 2

  const float* Ib = I + (size_t)batch * V_;
  const float* Jb = J + (size_t)batch * V_;
  const float* zp = zpad_g;

  // Staging chunks g0=tid, g1=tid+256 of 480. chunk g: arr=g/240, rem=g%240,
  // row r=rem/10 (h=h0-4+r), quad q=rem%10 (col=w0-4+4q, quad-aligned).
  const int g0 = tid, g1 = tid + 256;
  const int a0 = g0 / 240, rem0 = g0 % 240;
  const int r0 = rem0 / 10, q0 = rem0 % 10;
  const int h0g = h0 - 4 + r0, c0g = w0 - 4 + 4 * q0;
  const bool ok0 = ((unsigned)h0g < (unsigned)H_) && ((unsigned)c0g < (unsigned)W_);
  const float* gb0 = (a0 ? Jb : Ib) + (ok0 ? ((size_t)h0g * W_ + c0g) : 0);

  const int a1 = (g1 / 240) & 1, rem1 = g1 % 240;
  const int r1 = rem1 / 10, q1 = rem1 % 10;
  const int h1g = h0 - 4 + r1, c1g = w0 - 4 + 4 * q1;
  const bool okd1 = ((unsigned)h1g < (unsigned)H_) && ((unsigned)c1g < (unsigned)W_);
  const float* gb1 = (a1 ? Jb : Ib) + (okd1 ? ((size_t)h1g * W_ + c1g) : 0);

  // Wave-uniform LDS byte bases for the two DMA issues.
  const int wv  = tid >> 6;
  const int wb0 = wv * 1024;           // chunks [wv*64, wv*64+64)
  const int wb1 = 4096 + wv * 1024;    // chunks [256+wv*64, ...)

  // B mapping (tid < 192): wave w -> rows 8w+(tid&7), run (tid>>3)&7.
  // (row varies with LOW lane bits -> ws4-write bank starts all-distinct.)
  const int br = ((tid >> 6) << 3) | (tid & 7);
  const int brun = (tid >> 3) & 7;
  const int bc = brun * 4;

  // C mapping: col tx, output rows hb, hb+1
  const int tx = tid & 31;
  const int hb = (tid >> 5) * 2;

  unsigned ring[5][9];
  float sum0[5], sum1[5];
#pragma unroll
  for (int f = 0; f < 5; ++f) {
    sum0[f] = 0.f; sum1[f] = 0.f;
#pragma unroll
    for (int k = 0; k < 9; ++k) ring[f][k] = 0u;
  }

  float local = 0.f;

#pragma unroll 1
  for (int tb = 0; tb < 36; tb += 9) {
#pragma unroll
    for (int u = 0; u < 9; ++u) {
      const int t = tb + u;          // 0..35; phases self-guard (31..35 idle)

      // ---- stage: slice s = c0-4+t -> sIJ[t%3]; EVERY wave issues 2 DMAs ----
      if (t < DC + 8) {
        const int s = c0 - 4 + t;
        const bool sin = (unsigned)s < (unsigned)D_;
        const size_t so = sin ? (size_t)s * HW_ : 0;
        char* lbase = (char*)&sIJ[u % 3][0];   // t%3 == u%3 (tb multiple of 9)
        const float* A0 = (sin && ok0) ? (gb0 + so) : zp;
        GLD16(A0, lbase + wb0);
        if (g1 < 480) {                // lane-masked; still 1 issue per wave
          const float* A1 = (sin && okd1) ? (gb1 + so) : zp;
          GLD16(A1, lbase + wb1);
        }
      }

      // ---- C: H-dir 9-sums of ws (= slice t-3) + bf16 D-ring (slot u) ----
      if (t >= 3 && t < DC + 11) {
        float v0 = 0.f, v1 = 0.f, v2 = 0.f, v3 = 0.f, v4 = 0.f;
        float k00, k01, k02, k03, k04;
#pragma unroll
        for (int k = 0; k < 9; ++k) {
          const float4 a4 = ws4[hb + k][tx];
          const float2 p01 = unpack_bf2(__float_as_uint(a4.x));
          const float2 p23 = unpack_bf2(__float_as_uint(a4.y));
          if (k == 0) { k00 = p01.x; k01 = p01.y; k02 = p23.x; k03 = p23.y; k04 = a4.z; }
          v0 += p01.x; v1 += p01.y; v2 += p23.x; v3 += p23.y; v4 += a4.z;
        }
        const float4 t4 = ws4[hb + 9][tx];
        const float2 t01 = unpack_bf2(__float_as_uint(t4.x));
        const float2 t23 = unpack_bf2(__float_as_uint(t4.y));
        float hv0[5], hv1[5];
        hv0[0] = v0; hv0[1] = v1; hv0[2] = v2; hv0[3] = v3; hv0[4] = v4;
        hv1[0] = v0 + t01.x - k00;
        hv1[1] = v1 + t01.y - k01;
        hv1[2] = v2 + t23.x - k02;
        hv1[3] = v3 + t23.y - k03;
        hv1[4] = v4 + t4.z  - k04;

#pragma unroll
        for (int f = 0; f < 5; ++f) {
          const float2 old = unpack_bf2(ring[f][u]);
          sum0[f] += hv0[f] - old.x;
          sum1[f] += hv1[f] - old.y;
          ring[f][u] = pack_bf2(hv0[f], hv1[f]);
        }

        if (t >= 11) {
          const float inv = 1.f / 729.f;
          const float cx0 = sum0[4] - sum0[0] * sum0[1] * inv;
          const float iv0 = sum0[2] - sum0[0] * sum0[0] * inv;
          const float jv0 = sum0[3] - sum0[1] * sum0[1] * inv;
          local += cx0 * cx0 * __builtin_amdgcn_rcpf(iv0 * jv0 + 1e-5f);
          const float cx1 = sum1[4] - sum1[0] * sum1[1] * inv;
          const float iv1 = sum1[2] - sum1[0] * sum1[0] * inv;
          const float jv1 = sum1[3] - sum1[1] * sum1[1] * inv;
          local += cx1 * cx1 * __builtin_amdgcn_rcpf(iv1 * jv1 + 1e-5f);
        }
      }

      // ---- mid barrier: drain slice t-2 (stage(t), stage(t-1) in flight).
      //      Also covers the ws WAR (C reads above, B writes below).
      if (t >= 2 && t < DC + 10) {
        if (t < DC + 8) {
          asm volatile("s_waitcnt vmcnt(4)" ::: "memory");
        } else if (t == DC + 8) {
          asm volatile("s_waitcnt vmcnt(2)" ::: "memory");
        } else {
          asm volatile("s_waitcnt vmcnt(0)" ::: "memory");
        }
        __builtin_amdgcn_s_barrier();
      }

      // ---- B: W-dir 9-sums of slice t-2 from sIJ[(t-2)%3] -> packed ws ----
      if (t >= 2 && t < DC + 10 && tid < 192) {
        const float4* SI = &sIJ[(u + 1) % 3][br * 10 + brun];  // (t-2)%3
        const float4* SJ = SI + 240;
        const float4 A0 = SI[0], A1 = SI[1], A2 = SI[2];
        const float4 B0 = SJ[0], B1 = SJ[1], B2 = SJ[2];
        const float ai[12] = {A0.x,A0.y,A0.z,A0.w, A1.x,A1.y,A1.z,A1.w,
                              A2.x,A2.y,A2.z,A2.w};
        const float aj[12] = {B0.x,B0.y,B0.z,B0.w, B1.x,B1.y,B1.z,B1.w,
                              B2.x,B2.y,B2.z,B2.w};
        float4* W4 = ws4[br];
        float s0 = 0.f, s1 = 0.f, s2 = 0.f, s3 = 0.f, s4 = 0.f;
#pragma unroll
        for (int k = 0; k < 9; ++k) {
          const float a = ai[k], b = aj[k];
          s0 += a; s1 += b; s2 += a * a; s3 += b * b; s4 += a * b;
        }
        W4[bc] = make_float4(__uint_as_float(pack_bf2(s0, s1)),
                             __uint_as_float(pack_bf2(s2, s3)), s4, 0.f);
#pragma unroll
        for (int m = 1; m < 4; ++m) {
          const float ea = ai[8 + m], eb = aj[8 + m];
          const float la = ai[m - 1], lb = aj[m - 1];
          s0 += ea - la;
          s1 += eb - lb;
          s2 += ea * ea - la * la;
          s3 += eb * eb - lb * lb;
          s4 += ea * eb - la * lb;
          W4[bc + m] = make_float4(__uint_as_float(pack_bf2(s0, s1)),
                                   __uint_as_float(pack_bf2(s2, s3)), s4, 0.f);
        }
      }

      // ---- end barrier: ws RAW to C(t+1); sIJ[(t+1)%3] readers (B(t)) done
      //      before stage(t+1) overwrites it.
      if (t >= 2 && t < DC + 10) {
        asm volatile("s_waitcnt lgkmcnt(0)" ::: "memory");
        __builtin_amdgcn_s_barrier();
      }
    }
  }

  // ---- block reduction (reuse ws4 space) -> per-block partial ----
  __syncthreads();   // C(30)'s ws reads consumed before the space is reused
  float* red = (float*)&ws4[0][0];
  red[tid] = local;
  __syncthreads();
  for (int s2 = 128; s2 > 0; s2 >>= 1) {
    if (tid < s2) red[tid] += red[tid + s2];
    __syncthreads();
  }
  if (tid == 0) {
    const int bid = (blockIdx.z * 12 + blockIdx.y) * 5 + blockIdx.x;
    bsum[bid] = red[0];
  }
}

__global__ __launch_bounds__(256) void finalize_k(const float* __restrict__ bsum,
                                                  float* __restrict__ out) {
  __shared__ double red[256];
  double d = 0.0;
  for (int i = threadIdx.x; i < NBLOCKS; i += 256) d += (double)bsum[i];
  red[threadIdx.x] = d;
  __syncthreads();
  for (int s = 128; s > 0; s >>= 1) {
    if (threadIdx.x < s) red[threadIdx.x] += red[threadIdx.x + s];
    __syncthreads();
  }
  if (threadIdx.x == 0) out[0] = (float)(-red[0] / (double)NTOT);
}

extern "C" void kernel_launch(void* const* d_in, const int* in_sizes, int n_in,
                              void* d_out, int out_size, void* d_ws, size_t ws_size,
                              hipStream_t stream) {
  const float* I = (const float*)d_in[0];   // y_true
  const float* J = (const float*)d_in[1];   // y_pred
  float* out = (float*)d_out;
  float* bsum = (float*)d_ws;               // 960 floats

  dim3 grid(W_ / TW, H_ / TH, NCHUNK * 2);  // 5 x 12 x 16 = 960 blocks
  ncc_fused<<<grid, 256, 0, stream>>>(I, J, bsum);
  finalize_k<<<1, 256, 0, stream>>>(bsum, out);
}

// Round 6
// 148.065 us; speedup vs baseline: 1.3538x; 1.1631x over previous
//
#include <hip/hip_runtime.h>

#define D_ 160
#define H_ 192
#define W_ 160
#define HW_ (H_*W_)
#define V_ (D_*H_*W_)
#define NTOT (2*V_)

#define TW 32
#define TH 16
#define DC 40
#define NCHUNK (D_/DC)    // 4
#define RH 24             // TH + 8 halo
#define TWP 33            // ws stride pad
#define NBLOCKS (5*12*NCHUNK*2)   // 480

// 16B zero page for boundary/out-of-range DMA sources (L2-resident; keeps
// per-wave global_load_lds issue count uniform so counted vmcnt is sound).
__device__ __align__(64) float zpad_g[4] = {0.f, 0.f, 0.f, 0.f};

// 16B global->LDS DMA. LDS dest = wave-uniform base + lane*16 (m97/m104).
#define GLD16(gp, lp) \
  __builtin_amdgcn_global_load_lds( \
      (const __attribute__((address_space(1))) unsigned int*)(const void*)(gp), \
      (__attribute__((address_space(3))) unsigned int*)(void*)(lp), 16, 0, 0)

// RTNE f32x2 -> packed bf16x2 and back (validated R5/R6/R8: absmax 0.0).
__device__ inline unsigned pack_bf2(float a, float b) {
  unsigned ua = __float_as_uint(a), ub = __float_as_uint(b);
  ua += 0x7fffu + ((ua >> 16) & 1u);
  ub += 0x7fffu + ((ub >> 16) & 1u);
  return (ua & 0xffff0000u) | (ub >> 16);
}
__device__ inline float2 unpack_bf2(unsigned u) {
  return make_float2(__uint_as_float(u & 0xffff0000u),
                     __uint_as_float(u << 16));
}

// ---------------------------------------------------------------------------
// Fused separable 9x9x9 box filter + NCC.
// R9:  counted vmcnt + raw barriers: 111 -> 87 us.
// R10: FAILED: launch_bounds(256,4) reg-guarantee spilled (97MB scratch).
// R11: NEUTRAL: residency/prefetch don't move it.
// R12: FAILED: TH=24 ring state spilled (134MB scratch).
// R13: HURT: bf16-packed ws cut LDS traffic but added MORE VALU (39->53%
//      busy, 86->95us). KEY FINDING: wall ~= LDS cycles + VALU cycles SUMMED
//      (R11: 4650+2760~=6900/step; R13: 3400+4040~=7630). The lock-step
//      2-barrier phase structure keeps the two pipes from overlapping.
// R14: overlap the pipes.
//  (a) ONE barrier per step: with ws double-buffered, a single top-of-step
//      "s_waitcnt vmcnt(2) lgkmcnt(0); s_barrier" covers: B(t)'s staged-slice
//      drain (slice t-2; stage(t-1) stays in flight), C(t) <- B(t-1) ws RAW,
//      and stage(t) overwriting the sIJ buffer B(t-1) read. C(t) reads
//      ws[(t+1)&1] while B(t) writes ws[t&1] -> no intra-step hazard -> C and
//      B form ONE scheduling region; compiler interleaves LDS and VALU.
//  (b) DC 20->40 (grid 480): halo amortization 48/40 vs 28/20; block-steps
//      960x30 -> 480x51 = 0.85x; FETCH -12%. LDS 54720B -> 2/CU, 512 slots
//      >= 480 blocks -> single round.
//  (c) ws pack reverted (R13's VALU tax); R13's B-row bank-fix kept.
// Pipeline (u = t mod 9; t%3 == u%3 since 9%3==0; t in [0,54)):
//   top-bar(t): vmcnt(2|0) lgkmcnt(0) + s_barrier   t in [2,51)
//   stage(t):   slice t -> sIJ[t%3]                 t in [0,48)
//   C(t):       ws[(t+1)&1] (slice t-3) H-sums + D-ring   t in [3,51), emit t>=11
//   B(t):       sIJ[(t-2)%3] -> W-sums -> ws[t&1]   t in [2,50)
// ---------------------------------------------------------------------------
__global__ __launch_bounds__(256, 3) void ncc_fused(const float* __restrict__ I,
                                                    const float* __restrict__ J,
                                                    float* __restrict__ bsum) {
  __shared__ float4 sIJ[3][480];        // 23040 B [buf][ I 0..239 | J 240..479 ]
  __shared__ float4 ws4[2][RH][TWP];    // 25344 B W-sums f0-3, double-buffered
  __shared__ float  ws1[2][RH][TWP];    //  6336 B W-sums f4,   double-buffered
                                        // total 54720 B -> 2 blocks/CU

  const int tid = threadIdx.x;
  const int w0 = blockIdx.x * TW;               // 5
  const int h0 = blockIdx.y * TH;               // 12
  const int c0 = (blockIdx.z % NCHUNK) * DC;    // 4 chunks
  const int batch = blockIdx.z / NCHUNK;        // 2

  const float* Ib = I + (size_t)batch * V_;
  const float* Jb = J + (size_t)batch * V_;
  const float* zp = zpad_g;

  // Staging chunks g0=tid, g1=tid+256 of 480. chunk g: arr=g/240, rem=g%240,
  // row r=rem/10 (h=h0-4+r), quad q=rem%10 (col=w0-4+4q, quad-aligned).
  const int g0 = tid, g1 = tid + 256;
  const int a0 = g0 / 240, rem0 = g0 % 240;
  const int r0 = rem0 / 10, q0 = rem0 % 10;
  const int h0g = h0 - 4 + r0, c0g = w0 - 4 + 4 * q0;
  const bool ok0 = ((unsigned)h0g < (unsigned)H_) && ((unsigned)c0g < (unsigned)W_);
  const float* gb0 = (a0 ? Jb : Ib) + (ok0 ? ((size_t)h0g * W_ + c0g) : 0);

  const int a1 = (g1 / 240) & 1, rem1 = g1 % 240;
  const int r1 = rem1 / 10, q1 = rem1 % 10;
  const int h1g = h0 - 4 + r1, c1g = w0 - 4 + 4 * q1;
  const bool okd1 = ((unsigned)h1g < (unsigned)H_) && ((unsigned)c1g < (unsigned)W_);
  const float* gb1 = (a1 ? Jb : Ib) + (okd1 ? ((size_t)h1g * W_ + c1g) : 0);

  // Wave-uniform LDS byte bases for the two DMA issues.
  const int wv  = tid >> 6;
  const int wb0 = wv * 1024;           // chunks [wv*64, wv*64+64)
  const int wb1 = 4096 + wv * 1024;    // chunks [256+wv*64, ...)

  // B mapping (tid < 192): wave w -> rows 8w+(tid&7), run (tid>>3)&7.
  // (row varies with LOW lane bits -> ws4-write bank starts spread; R13 fix.)
  const int br = ((tid >> 6) << 3) | (tid & 7);
  const int brun = (tid >> 3) & 7;
  const int bc = brun * 4;

  // C mapping: col tx, output rows hb, hb+1
  const int tx = tid & 31;
  const int hb = (tid >> 5) * 2;

  unsigned ring[5][9];
  float sum0[5], sum1[5];
#pragma unroll
  for (int f = 0; f < 5; ++f) {
    sum0[f] = 0.f; sum1[f] = 0.f;
#pragma unroll
    for (int k = 0; k < 9; ++k) ring[f][k] = 0u;
  }

  float local = 0.f;

#pragma unroll 1
  for (int tb = 0; tb < 54; tb += 9) {
#pragma unroll
    for (int u = 0; u < 9; ++u) {
      const int t = tb + u;          // 0..53; phases self-guard (51..53 idle)

      // ---- top-of-step barrier: drains slice t-2 (vmcnt(2): stage(t-1)
      //      stays in flight), makes B(t-1)'s ws writes visible, and protects
      //      sIJ[t%3] (read by B(t-1)) from stage(t)'s DMA. ----
      if (t >= 2 && t < DC + 11) {
        if (t < DC + 9) {
          asm volatile("s_waitcnt vmcnt(2) lgkmcnt(0)" ::: "memory");
        } else {
          asm volatile("s_waitcnt vmcnt(0) lgkmcnt(0)" ::: "memory");
        }
        __builtin_amdgcn_s_barrier();
      }

      // ---- stage: slice s = c0-4+t -> sIJ[t%3]; EVERY wave issues 2 DMAs ----
      if (t < DC + 8) {
        const int s = c0 - 4 + t;
        const bool sin = (unsigned)s < (unsigned)D_;
        const size_t so = sin ? (size_t)s * HW_ : 0;
        char* lbase = (char*)&sIJ[u % 3][0];   // t%3 == u%3 (tb multiple of 9)
        const float* A0 = (sin && ok0) ? (gb0 + so) : zp;
        GLD16(A0, lbase + wb0);
        if (g1 < 480) {                // lane-masked; still 1 issue per wave
          const float* A1 = (sin && okd1) ? (gb1 + so) : zp;
          GLD16(A1, lbase + wb1);
        }
      }

      // ---- C: H-dir 9-sums of ws[(t+1)&1] (= slice t-3) + bf16 D-ring ----
      if (t >= 3 && t < DC + 11) {
        const float4 (*W4r)[TWP] = ws4[(t + 1) & 1];
        const float  (*W1r)[TWP] = ws1[(t + 1) & 1];
        float v0 = 0.f, v1 = 0.f, v2 = 0.f, v3 = 0.f, v4 = 0.f;
        float4 k4; float k1v;
#pragma unroll
        for (int k = 0; k < 9; ++k) {
          const float4 a4 = W4r[hb + k][tx];
          const float  a1f = W1r[hb + k][tx];
          if (k == 0) { k4 = a4; k1v = a1f; }
          v0 += a4.x; v1 += a4.y; v2 += a4.z; v3 += a4.w; v4 += a1f;
        }
        const float4 t4 = W4r[hb + 9][tx];
        const float  t1 = W1r[hb + 9][tx];
        float hv0[5], hv1[5];
        hv0[0] = v0; hv0[1] = v1; hv0[2] = v2; hv0[3] = v3; hv0[4] = v4;
        hv1[0] = v0 + t4.x - k4.x;
        hv1[1] = v1 + t4.y - k4.y;
        hv1[2] = v2 + t4.z - k4.z;
        hv1[3] = v3 + t4.w - k4.w;
        hv1[4] = v4 + t1   - k1v;

#pragma unroll
        for (int f = 0; f < 5; ++f) {
          const float2 old = unpack_bf2(ring[f][u]);
          sum0[f] += hv0[f] - old.x;
          sum1[f] += hv1[f] - old.y;
          ring[f][u] = pack_bf2(hv0[f], hv1[f]);
        }

        if (t >= 11) {
          const float inv = 1.f / 729.f;
          const float cx0 = sum0[4] - sum0[0] * sum0[1] * inv;
          const float iv0 = sum0[2] - sum0[0] * sum0[0] * inv;
          const float jv0 = sum0[3] - sum0[1] * sum0[1] * inv;
          local += cx0 * cx0 * __builtin_amdgcn_rcpf(iv0 * jv0 + 1e-5f);
          const float cx1 = sum1[4] - sum1[0] * sum1[1] * inv;
          const float iv1 = sum1[2] - sum1[0] * sum1[0] * inv;
          const float jv1 = sum1[3] - sum1[1] * sum1[1] * inv;
          local += cx1 * cx1 * __builtin_amdgcn_rcpf(iv1 * jv1 + 1e-5f);
        }
      }

      // ---- B: W-dir 9-sums of slice t-2 from sIJ[(t-2)%3] -> ws[t&1] ----
      //      (same region as C: no barrier between them; pipes interleave)
      if (t >= 2 && t < DC + 10 && tid < 192) {
        const float4* SI = &sIJ[(u + 1) % 3][br * 10 + brun];  // (t-2)%3
        const float4* SJ = SI + 240;
        const float4 A0 = SI[0], A1 = SI[1], A2 = SI[2];
        const float4 B0 = SJ[0], B1 = SJ[1], B2 = SJ[2];
        const float ai[12] = {A0.x,A0.y,A0.z,A0.w, A1.x,A1.y,A1.z,A1.w,
                              A2.x,A2.y,A2.z,A2.w};
        const float aj[12] = {B0.x,B0.y,B0.z,B0.w, B1.x,B1.y,B1.z,B1.w,
                              B2.x,B2.y,B2.z,B2.w};
        float4* W4 = ws4[t & 1][br];
        float*  W1 = ws1[t & 1][br];
        float s0 = 0.f, s1 = 0.f, s2 = 0.f, s3 = 0.f, s4 = 0.f;
#pragma unroll
        for (int k = 0; k < 9; ++k) {
          const float a = ai[k], b = aj[k];
          s0 += a; s1 += b; s2 += a * a; s3 += b * b; s4 += a * b;
        }
        W4[bc] = make_float4(s0, s1, s2, s3);
        W1[bc] = s4;
#pragma unroll
        for (int m = 1; m < 4; ++m) {
          const float ea = ai[8 + m], eb = aj[8 + m];
          const float la = ai[m - 1], lb = aj[m - 1];
          s0 += ea - la;
          s1 += eb - lb;
          s2 += ea * ea - la * la;
          s3 += eb * eb - lb * lb;
          s4 += ea * eb - la * lb;
          W4[bc + m] = make_float4(s0, s1, s2, s3);
          W1[bc + m] = s4;
        }
      }
    }
  }

  // ---- block reduction (reuse ws4 space) -> per-block partial ----
  __syncthreads();   // C(50)'s ws reads consumed before the space is reused
  float* red = (float*)&ws4[0][0][0];
  red[tid] = local;
  __syncthreads();
  for (int s2 = 128; s2 > 0; s2 >>= 1) {
    if (tid < s2) red[tid] += red[tid + s2];
    __syncthreads();
  }
  if (tid == 0) {
    const int bid = (blockIdx.z * 12 + blockIdx.y) * 5 + blockIdx.x;
    bsum[bid] = red[0];
  }
}

__global__ __launch_bounds__(256) void finalize_k(const float* __restrict__ bsum,
                                                  float* __restrict__ out) {
  __shared__ double red[256];
  double d = 0.0;
  for (int i = threadIdx.x; i < NBLOCKS; i += 256) d += (double)bsum[i];
  red[threadIdx.x] = d;
  __syncthreads();
  for (int s = 128; s > 0; s >>= 1) {
    if (threadIdx.x < s) red[threadIdx.x] += red[threadIdx.x + s];
    __syncthreads();
  }
  if (threadIdx.x == 0) out[0] = (float)(-red[0] / (double)NTOT);
}

extern "C" void kernel_launch(void* const* d_in, const int* in_sizes, int n_in,
                              void* d_out, int out_size, void* d_ws, size_t ws_size,
                              hipStream_t stream) {
  const float* I = (const float*)d_in[0];   // y_true
  const float* J = (const float*)d_in[1];   // y_pred
  float* out = (float*)d_out;
  float* bsum = (float*)d_ws;               // 480 floats

  dim3 grid(W_ / TW, H_ / TH, NCHUNK * 2);  // 5 x 12 x 8 = 480 blocks
  ncc_fused<<<grid, 256, 0, stream>>>(I, J, bsum);
  finalize_k<<<1, 256, 0, stream>>>(bsum, out);
}